// Round 18
// baseline (311.268 us; speedup 1.0000x reference)
//
#include <hip/hip_runtime.h>
#include <cstdint>

typedef unsigned short u16;
typedef __attribute__((ext_vector_type(8))) short bf16x8;
typedef __attribute__((ext_vector_type(4))) float f32x4;

__device__ __forceinline__ u16 f2b(float x) {
  unsigned u = __float_as_uint(x);
  u += 0x7FFFu + ((u >> 16) & 1u);
  return (u16)(u >> 16);
}

__device__ __forceinline__ void gload16(const void* g, void* l) {
  __builtin_amdgcn_global_load_lds(
      (const __attribute__((address_space(1))) void*)g,
      (__attribute__((address_space(3))) void*)l, 16, 0, 0);
}

template <int N>
__device__ __forceinline__ void vmwait() {
  if constexpr (N == 0) asm volatile("s_waitcnt vmcnt(0)" ::: "memory");
  else if constexpr (N == 4) asm volatile("s_waitcnt vmcnt(4)" ::: "memory");
  else if constexpr (N == 6) asm volatile("s_waitcnt vmcnt(6)" ::: "memory");
}

// ---------------------------------------------------------------------------
// 128x32 bf16 slice as 64 virtual rows of 128 B (8 x 16 B chunks), chunk
// XOR (vrow&7): measured ZERO bank conflicts (r10-r17). Both-sides rule
// (m231): LDS dest linear, global source inverse-swizzled, read same
// involution.
// ---------------------------------------------------------------------------
__device__ __forceinline__ void stage128(const u16* __restrict__ G,
                                         long long ld, int kb,
                                         u16* Ldst, int tid) {
#pragma unroll
  for (int j = 0; j < 2; ++j) {
    const int P = j * 256 + tid;
    const int vr = P >> 3;
    const int ch = (P & 7) ^ (vr & 7);
    const int r = vr * 2 + (ch >> 2), c = ch & 3;
    gload16(G + (long long)r * ld + kb + c * 8, Ldst + P * 8);
  }
}

__device__ __forceinline__ bf16x8 fr4(const u16* R, int row, int chunk) {
  const int vr = row >> 1;
  const int ch = (((row & 1) << 2) | chunk) ^ (vr & 7);
  return *(const bf16x8*)(R + vr * 64 + ch * 8);
}

// XCD-aware bijective swizzle within a role's sub-grid (S % 8 == 0)
__device__ __forceinline__ void swz_xcd(int hw, int S, int gx,
                                        int& bx, int& by) {
  const int l = (hw & 7) * (S >> 3) + (hw >> 3);
  bx = l % gx;
  by = l / gx;
}

// ---------------------------------------------------------------------------
// gemm_core: 128x128 tile, BK=32, 4 waves (wave 64x64), 3x16KB LDS,
// depth-2 counted vmcnt(4). 741 TF class (r10-r15).
// EPI: 0=QK split  1=theta->cat half  2=bf16  3=f32+colbias  4=f32 plain
// ---------------------------------------------------------------------------
template <int EPI>
__device__ __forceinline__ void gemm_core(
    u16* lds, int bx, int by, int z,
    const u16* __restrict__ A, long long lda, long long sAz,
    const u16* __restrict__ B, long long ldb, long long sBz,
    void* __restrict__ C0, void* __restrict__ C1,
    long long ldc, long long sCz, int K,
    const float* __restrict__ b0, const float* __restrict__ b1,
    float preScale, const float* __restrict__ esp) {
  constexpr int HALF = 4096;
  constexpr int BUFU = 2 * HALF;
  const long long tM = (long long)by * 128;
  const long long tN = (long long)bx * 128;
  const u16* GA = A + z * sAz + tM * lda;
  const u16* GB = B + z * sBz + tN * ldb;
  const int tid = threadIdx.x;
  const int NT = K >> 5;

  stage128(GA, lda, 0, lds, tid);
  stage128(GB, ldb, 0, lds + HALF, tid);
  stage128(GA, lda, 32, lds + BUFU, tid);
  stage128(GB, ldb, 32, lds + BUFU + HALF, tid);

  const int wid = tid >> 6, lane = tid & 63;
  const int wr = (wid >> 1) * 64, wc = (wid & 1) * 64;
  const int lr = lane & 15, cA = lane >> 4;
  f32x4 acc[4][4] = {};

  for (int t = 0; t < NT; ++t) {
    if (t < NT - 1) vmwait<4>(); else vmwait<0>();
    __builtin_amdgcn_s_barrier();
    if (t + 2 < NT) {
      u16* nxt = lds + ((t + 2) % 3) * BUFU;
      stage128(GA, lda, (t + 2) * 32, nxt, tid);
      stage128(GB, ldb, (t + 2) * 32, nxt + HALF, tid);
    }
    const u16* cur = lds + (t % 3) * BUFU;
    bf16x8 a[4], b[4];
#pragma unroll
    for (int m = 0; m < 4; ++m) a[m] = fr4(cur, wr + m * 16 + lr, cA);
#pragma unroll
    for (int n = 0; n < 4; ++n) b[n] = fr4(cur + HALF, wc + n * 16 + lr, cA);
#pragma unroll
    for (int m = 0; m < 4; ++m)
#pragma unroll
      for (int n = 0; n < 4; ++n)
        acc[m][n] = __builtin_amdgcn_mfma_f32_16x16x32_bf16(a[m], b[n],
                                                            acc[m][n], 0, 0, 0);
  }

  const int rr = (lane >> 4) << 2;
  float ps = preScale, mul = 1.0f;
  if constexpr (EPI == 1) {
    ps = (z == 0) ? preScale : 1.0f;
    mul = (z == 0) ? esp[0] : 1.0f;
  }
#pragma unroll
  for (int m = 0; m < 4; ++m) {
#pragma unroll
    for (int n = 0; n < 4; ++n) {
      const int col = (int)tN + wc + n * 16 + lr;
#pragma unroll
      for (int r = 0; r < 4; ++r) {
        const long long row = tM + wr + m * 16 + rr + r;
        const float v = acc[m][n][r];
        if constexpr (EPI == 0) {
          const int g = col >> 10, cc = col & 1023;
          if (g == 0) ((u16*)C0)[row * 2048 + cc] = f2b((v + b0[cc]) * 0.03125f);
          else        ((u16*)C1)[row * 2048 + cc] = f2b(v + b1[cc]);
        } else if constexpr (EPI == 1) {
          const float tt = v * ps + b0[col];
          const float sg = 1.f / (1.f + __expf(-tt));
          ((u16*)C0)[z * sCz + row * ldc + col] = f2b(mul * cospif(sg));
        } else if constexpr (EPI == 2) {
          ((u16*)C0)[z * sCz + row * ldc + col] = f2b(v);
        } else if constexpr (EPI == 3) {
          ((float*)C0)[z * sCz + row * ldc + col] = v + b0[col];
        } else {
          ((float*)C0)[z * sCz + row * ldc + col] = v;
        }
      }
    }
  }
}

// ---------------------------------------------------------------------------
// wide_core: A-frag-reuse wide-wave GEMM (r15: 857 TF, MfmaUtil 36%).
// Block 128x256, BK=32, 4 waves (2Mx2N), wave 64x128: 12 ds_read_b128 per
// 32 MFMA. 3x24KB LDS (2 blocks/CU), depth-2 counted vmcnt(6).
// EPI: 4=f32 plain (scores)
// ---------------------------------------------------------------------------
template <int EPI>
__device__ __forceinline__ void wide_core(
    u16* lds, int bx, int by, int z,
    const u16* __restrict__ A, long long lda, long long sAz,
    const u16* __restrict__ B, long long ldb, long long sBz,
    void* __restrict__ C0, void* __restrict__ C1,
    long long ldc, long long sCz, int K,
    const float* __restrict__ b0, const float* __restrict__ b1,
    float preScale, const float* __restrict__ esp) {
  constexpr int AS = 4096;            // u16: A slice 128x32
  constexpr int BUFU = AS + 8192;     // 24 KB
  const long long tM = (long long)by * 128;
  const long long tN = (long long)bx * 256;
  const u16* GA = A + z * sAz + tM * lda;
  const u16* GB = B + z * sBz + tN * ldb;
  const int tid = threadIdx.x;
  const int NT = K >> 5;

#define STAGE_W(kb, buf)                                         \
  do {                                                           \
    stage128(GA, lda, (kb), (buf), tid);                         \
    stage128(GB, ldb, (kb), (buf) + AS, tid);                    \
    stage128(GB + 128 * ldb, ldb, (kb), (buf) + AS + 4096, tid); \
  } while (0)

  STAGE_W(0, lds);
  STAGE_W(32, lds + BUFU);

  const int wid = tid >> 6, lane = tid & 63;
  const int wr = (wid >> 1) * 64, wc = (wid & 1) * 128;
  const int lr = lane & 15, cA = lane >> 4;
  f32x4 acc[4][8] = {};

  for (int t = 0; t < NT; ++t) {
    if (t < NT - 1) vmwait<6>(); else vmwait<0>();
    __builtin_amdgcn_s_barrier();
    if (t + 2 < NT) STAGE_W((t + 2) * 32, lds + ((t + 2) % 3) * BUFU);
    const u16* cur = lds + (t % 3) * BUFU;
    const u16* Bs = cur + AS + (wid & 1) * 4096;  // wave's 128-row B sub-slab
    bf16x8 a[4], b[8];
#pragma unroll
    for (int m = 0; m < 4; ++m) a[m] = fr4(cur, wr + m * 16 + lr, cA);
#pragma unroll
    for (int n = 0; n < 8; ++n) b[n] = fr4(Bs, n * 16 + lr, cA);
#pragma unroll
    for (int m = 0; m < 4; ++m)
#pragma unroll
      for (int n = 0; n < 8; ++n)
        acc[m][n] = __builtin_amdgcn_mfma_f32_16x16x32_bf16(a[m], b[n],
                                                            acc[m][n], 0, 0, 0);
  }
#undef STAGE_W

  const int rr = (lane >> 4) << 2;
#pragma unroll
  for (int m = 0; m < 4; ++m) {
#pragma unroll
    for (int n = 0; n < 8; ++n) {
      const int col = (int)tN + wc + n * 16 + lr;
#pragma unroll
      for (int r = 0; r < 4; ++r) {
        const long long row = tM + wr + m * 16 + rr + r;
        ((float*)C0)[z * sCz + row * ldc + col] = acc[m][n][r];
      }
    }
  }
}

// scores: logits = Qcat @ Kcat^T (wide, f32 out), grid 512 @2/CU exact fill
__global__ __launch_bounds__(256, 2) void e3s(
    const u16* __restrict__ A, long long lda, long long sAz,
    const u16* __restrict__ B, long long ldb, long long sBz,
    float* __restrict__ C, long long ldc, long long sCz, int K) {
  __shared__ __align__(16) u16 lds[3 * 12288];
  int bx, by;
  swz_xcd(blockIdx.y * gridDim.x + blockIdx.x, gridDim.x * gridDim.y,
          gridDim.x, bx, by);
  wide_core<4>(lds, bx, by, blockIdx.z, A, lda, sAz, B, ldb, sBz,
               C, nullptr, ldc, sCz, K, nullptr, nullptr, 1.f, nullptr);
}

// final: out = ATT @ XVT^T + bfin (narrow, 512 blocks @ 3/CU)
template <int EPI>
__global__ __launch_bounds__(256, 3) void e3p(
    const u16* __restrict__ A, long long lda, long long sAz,
    const u16* __restrict__ B, long long ldb, long long sBz,
    void* __restrict__ C0, long long ldc, long long sCz, int K,
    const float* __restrict__ b0) {
  __shared__ __align__(16) u16 lds[3 * 8192];
  int bx, by;
  swz_xcd(blockIdx.y * gridDim.x + blockIdx.x, gridDim.x * gridDim.y,
          gridDim.x, bx, by);
  gemm_core<EPI>(lds, bx, by, blockIdx.z, A, lda, sAz, B, ldb, sBz,
                 C0, nullptr, ldc, sCz, K, b0, nullptr, 1.f, nullptr);
}

// merged narrow (r15-proven): QK projection (0..1023) + WvoT prep (1024..1087)
// 1088 blocks @ 3/CU
__global__ __launch_bounds__(256, 3) void qk_wvo(
    const u16* __restrict__ XB, u16* __restrict__ WT,
    u16* __restrict__ Qc, u16* __restrict__ Kc,
    const float* __restrict__ bq, const float* __restrict__ bk) {
  __shared__ __align__(16) u16 lds[3 * 8192];
  const int id = blockIdx.x;
  if (id < 1024) {
    int bx, by;
    swz_xcd(id, 1024, 16, bx, by);
    gemm_core<0>(lds, bx, by, 0, XB, 1024, 0, WT, 1024, 0,
                 Qc, Kc, 2048, 0, 1024, bq, bk, 1.f, nullptr);
  } else {
    int bx, by;
    swz_xcd(id - 1024, 64, 8, bx, by);
    gemm_core<2>(lds, bx, by, 0, WT + (3LL << 20), 1024, 0,
                 WT + (4LL << 20), 1024, 0, WT + (5LL << 20), nullptr,
                 1024, 0, 1024, nullptr, nullptr, 1.f, nullptr);
  }
}

// merged narrow INTERLEAVED: 1536 blocks @ 3/CU = 2 exact rounds.
// id%3<2 -> theta (1024 blocks), id%3==2 -> XVT (512 blocks).
// Interleave makes each CU's 3 resident blocks a role MIX so theta's
// VALU-heavy transcendental epilogue overlaps XVT's MFMA mainloop (m114).
__global__ __launch_bounds__(256, 3) void theta_xvt(
    u16* __restrict__ Qcat, const u16* __restrict__ WT,
    const u16* __restrict__ XB, u16* __restrict__ XVT_,
    const float* __restrict__ bt, const float* __restrict__ esp) {
  __shared__ __align__(16) u16 lds[3 * 8192];
  const int id = blockIdx.x;
  const int trip = id / 3, rem = id - trip * 3;
  if (rem < 2) {
    const int tix = trip * 2 + rem;       // 0..1023
    const int z = tix >> 9;
    int bx, by;
    swz_xcd(tix & 511, 512, 8, bx, by);
    gemm_core<1>(lds, bx, by, z, Qcat, 2048, 16777216LL,
                 WT + (2LL << 20), 1024, 0, Qcat + 1024, nullptr,
                 2048, 16777216LL, 1024, bt, nullptr, 32.f, esp);
  } else {
    const int e = trip;                   // 0..511
    const int z = e >> 7;
    int bx, by;
    swz_xcd(e & 127, 128, 16, bx, by);
    gemm_core<2>(lds, bx, by, z, WT + (5LL << 20), 1024, 0,
                 XB, 1024, 2097152LL, XVT_, nullptr,
                 2048, 2097152LL, 1024, nullptr, nullptr, 1.f, nullptr);
  }
}

// merged prep: cvt_x (0..8191) + cvt_w (8192..13311) + bias_fold (13312..14335)
__global__ __launch_bounds__(256) void prep_all(
    const float* __restrict__ x,
    const float* __restrict__ Wq, const float* __restrict__ Wk,
    const float* __restrict__ Wt, const float* __restrict__ Wo,
    const float* __restrict__ Wv, const float* __restrict__ bv,
    const float* __restrict__ bo,
    u16* __restrict__ XB, u16* __restrict__ WT, float* __restrict__ BF) {
  __shared__ float sh[32][33];
  const int id = blockIdx.x;
  const int thr = threadIdx.x;
  if (id < 8192) {
    const int i = id * 256 + thr;
    float4 v = ((const float4*)x)[i];
    ((ushort4*)XB)[i] = make_ushort4(f2b(v.x), f2b(v.y), f2b(v.z), f2b(v.w));
  } else if (id < 13312) {
    const int w = id - 8192;
    const int z = w >> 10, rem = w & 1023;
    const int cx = rem & 31, cy = rem >> 5;
    const float* W = (z == 0) ? Wq : (z == 1) ? Wk : (z == 2) ? Wt
                   : (z == 3) ? Wo : Wv;
    u16* D = WT + ((long long)z << 20);
    const int c0 = cx * 32, r0 = cy * 32;
    const int tx = thr & 31, ty = thr >> 5;
    if (z == 4) {
#pragma unroll
      for (int i = 0; i < 4; ++i) {
        const long long idx = (long long)(r0 + ty + i * 8) * 1024 + c0 + tx;
        D[idx] = f2b(W[idx]);
      }
      return;
    }
#pragma unroll
    for (int i = 0; i < 4; ++i)
      sh[ty + i * 8][tx] = W[(long long)(r0 + ty + i * 8) * 1024 + c0 + tx];
    __syncthreads();
#pragma unroll
    for (int i = 0; i < 4; ++i)
      D[(long long)(c0 + ty + i * 8) * 1024 + r0 + tx] = f2b(sh[tx][ty + i * 8]);
  } else {
    const int i = id - 13312;
    float acc = 0.f;
    for (int k = thr; k < 1024; k += 256)
      acc += bv[k] * Wo[(long long)k * 1024 + i];
    float* red = &sh[0][0];
    red[thr] = acc;
    __syncthreads();
    for (int s = 128; s > 0; s >>= 1) {
      if (thr < s) red[thr] += red[thr + s];
      __syncthreads();
    }
    if (thr == 0) BF[i] = red[0] + bo[i];
  }
}

// row softmax over [8192][2048]: fp32 in-place + bf16 copy
__global__ __launch_bounds__(256) void softmax_rows(float* __restrict__ L,
                                                    u16* __restrict__ AB) {
  const long long row = blockIdx.x;
  float4* p4 = (float4*)(L + row * 2048);
  const int tid = threadIdx.x;
  float4 a = p4[tid], b = p4[tid + 256];
  float m = fmaxf(fmaxf(fmaxf(a.x, a.y), fmaxf(a.z, a.w)),
                  fmaxf(fmaxf(b.x, b.y), fmaxf(b.z, b.w)));
#pragma unroll
  for (int o = 32; o > 0; o >>= 1) m = fmaxf(m, __shfl_xor(m, o));
  __shared__ float rmax[4], rsum[4];
  const int wid = tid >> 6, lane = tid & 63;
  if (lane == 0) rmax[wid] = m;
  __syncthreads();
  m = fmaxf(fmaxf(rmax[0], rmax[1]), fmaxf(rmax[2], rmax[3]));
  a.x = __expf(a.x - m); a.y = __expf(a.y - m);
  a.z = __expf(a.z - m); a.w = __expf(a.w - m);
  b.x = __expf(b.x - m); b.y = __expf(b.y - m);
  b.z = __expf(b.z - m); b.w = __expf(b.w - m);
  float s = a.x + a.y + a.z + a.w + b.x + b.y + b.z + b.w;
#pragma unroll
  for (int o = 32; o > 0; o >>= 1) s += __shfl_xor(s, o);
  if (lane == 0) rsum[wid] = s;
  __syncthreads();
  s = rsum[0] + rsum[1] + rsum[2] + rsum[3];
  const float inv = 1.0f / s;
  a.x *= inv; a.y *= inv; a.z *= inv; a.w *= inv;
  b.x *= inv; b.y *= inv; b.z *= inv; b.w *= inv;
  p4[tid] = a;
  p4[tid + 256] = b;
  ushort4* o4 = (ushort4*)(AB + row * 2048);
  o4[tid]       = make_ushort4(f2b(a.x), f2b(a.y), f2b(a.z), f2b(a.w));
  o4[tid + 256] = make_ushort4(f2b(b.x), f2b(b.y), f2b(b.z), f2b(b.w));
}

extern "C" void kernel_launch(void* const* d_in, const int* in_sizes, int n_in,
                              void* d_out, int out_size, void* d_ws,
                              size_t ws_size, hipStream_t stream) {
  const float* x  = (const float*)d_in[0];
  const float* Wq = (const float*)d_in[1];
  const float* bq = (const float*)d_in[2];
  const float* Wk = (const float*)d_in[3];
  const float* bk = (const float*)d_in[4];
  const float* Wv = (const float*)d_in[5];
  const float* bv = (const float*)d_in[6];
  const float* Wt = (const float*)d_in[7];
  const float* bt = (const float*)d_in[8];
  const float* Wo = (const float*)d_in[9];
  const float* bo = (const float*)d_in[10];
  const float* es = (const float*)d_in[11];

  char* ws = (char*)d_ws;
  // WT slots (1 MiB-u16 = 2 MB each): 0=WqT 1=WkT 2=WtT 3=WoT 4=WvB 5=WvoT
  u16* WT    = (u16*)(ws);                   // 12 MB
  float* BF  = (float*)(ws + 12582912);      // bfin[1024]
  u16* XB    = (u16*)(ws + 12587008);        // [8192,1024] bf16
  u16* Qcat  = (u16*)(ws + 29364224);        // [8192,2048]: Q/32 | es*r_q
  u16* Kcat  = Qcat + 16777216;              // [8192,2048]: K | r_k
  u16* XVT   = (u16*)(ws + 96473088);        // [4][1024,2048]: (x@Wvo)^T
  u16* ATT   = Qcat;                         // attn bf16 reuse

  float* outO = (float*)d_out;               // [4,2048,1024]
  float* outA = outO + 8388608;              // [4,2048,2048]

  // 1. all preps (cvt_x + cvt_w + bias_fold)
  prep_all<<<14336, 256, 0, stream>>>(x, Wq, Wk, Wt, Wo, Wv, bv, bo,
                                      XB, WT, BF);
  // 2. QK projection + WvoT prep (narrow, 1088 @ 3/CU)
  qk_wvo<<<1088, 256, 0, stream>>>(XB, WT, Qcat, Kcat, bq, bk);
  // 3. theta + XVT (narrow, 1536 @ 3/CU, INTERLEAVED roles)
  theta_xvt<<<1536, 256, 0, stream>>>(Qcat, WT, XB, XVT, bt, es);
  // 4. logits = Qcat @ Kcat^T (K=2048) -> outA (wide, grid 512 exact fill)
  e3s<<<dim3(8, 16, 4), 256, 0, stream>>>(
      Qcat, 2048, 4194304, Kcat, 2048, 4194304,
      outA, 2048, 4194304, 2048);
  // 5. softmax in-place + bf16 copy
  softmax_rows<<<8192, 256, 0, stream>>>(outA, ATT);
  // 6. out = ATT @ XVT^T + bfin (narrow, grid 512 @ 3/CU)
  e3p<3><<<dim3(8, 16, 4), 256, 0, stream>>>(
      ATT, 2048, 4194304, XVT, 2048, 2097152,
      outO, 1024, 2097152, 2048, BF);
}

// Round 19
// 306.463 us; speedup vs baseline: 1.0157x; 1.0157x over previous
//
#include <hip/hip_runtime.h>
#include <cstdint>

typedef unsigned short u16;
typedef __attribute__((ext_vector_type(8))) short bf16x8;
typedef __attribute__((ext_vector_type(4))) float f32x4;

__device__ __forceinline__ u16 f2b(float x) {
  unsigned u = __float_as_uint(x);
  u += 0x7FFFu + ((u >> 16) & 1u);
  return (u16)(u >> 16);
}

__device__ __forceinline__ void gload16(const void* g, void* l) {
  __builtin_amdgcn_global_load_lds(
      (const __attribute__((address_space(1))) void*)g,
      (__attribute__((address_space(3))) void*)l, 16, 0, 0);
}

template <int N>
__device__ __forceinline__ void vmwait() {
  if constexpr (N == 0) asm volatile("s_waitcnt vmcnt(0)" ::: "memory");
  else if constexpr (N == 4) asm volatile("s_waitcnt vmcnt(4)" ::: "memory");
  else if constexpr (N == 6) asm volatile("s_waitcnt vmcnt(6)" ::: "memory");
}

// ---------------------------------------------------------------------------
// 128x32 bf16 slice as 64 virtual rows of 128 B (8 x 16 B chunks), chunk
// XOR (vrow&7): measured ZERO bank conflicts (r10-r18). Both-sides rule
// (m231): LDS dest linear, global source inverse-swizzled, read same
// involution.
// ---------------------------------------------------------------------------
__device__ __forceinline__ void stage128(const u16* __restrict__ G,
                                         long long ld, int kb,
                                         u16* Ldst, int tid) {
#pragma unroll
  for (int j = 0; j < 2; ++j) {
    const int P = j * 256 + tid;
    const int vr = P >> 3;
    const int ch = (P & 7) ^ (vr & 7);
    const int r = vr * 2 + (ch >> 2), c = ch & 3;
    gload16(G + (long long)r * ld + kb + c * 8, Ldst + P * 8);
  }
}

__device__ __forceinline__ bf16x8 fr4(const u16* R, int row, int chunk) {
  const int vr = row >> 1;
  const int ch = (((row & 1) << 2) | chunk) ^ (vr & 7);
  return *(const bf16x8*)(R + vr * 64 + ch * 8);
}

// XCD-aware bijective swizzle within a role's sub-grid (S % 8 == 0)
__device__ __forceinline__ void swz_xcd(int hw, int S, int gx,
                                        int& bx, int& by) {
  const int l = (hw & 7) * (S >> 3) + (hw >> 3);
  bx = l % gx;
  by = l / gx;
}

// ---------------------------------------------------------------------------
// gemm_core: 128x128 tile, BK=32, 4 waves (wave 64x64), 3x16KB LDS,
// depth-2 counted vmcnt(4). 741 TF class (r10-r15).
// EPI: 0=QK split  1=theta->cat half  2=bf16  3=f32+colbias  4=f32 plain
// ---------------------------------------------------------------------------
template <int EPI>
__device__ __forceinline__ void gemm_core(
    u16* lds, int bx, int by, int z,
    const u16* __restrict__ A, long long lda, long long sAz,
    const u16* __restrict__ B, long long ldb, long long sBz,
    void* __restrict__ C0, void* __restrict__ C1,
    long long ldc, long long sCz, int K,
    const float* __restrict__ b0, const float* __restrict__ b1,
    float preScale, const float* __restrict__ esp) {
  constexpr int HALF = 4096;
  constexpr int BUFU = 2 * HALF;
  const long long tM = (long long)by * 128;
  const long long tN = (long long)bx * 128;
  const u16* GA = A + z * sAz + tM * lda;
  const u16* GB = B + z * sBz + tN * ldb;
  const int tid = threadIdx.x;
  const int NT = K >> 5;

  stage128(GA, lda, 0, lds, tid);
  stage128(GB, ldb, 0, lds + HALF, tid);
  stage128(GA, lda, 32, lds + BUFU, tid);
  stage128(GB, ldb, 32, lds + BUFU + HALF, tid);

  const int wid = tid >> 6, lane = tid & 63;
  const int wr = (wid >> 1) * 64, wc = (wid & 1) * 64;
  const int lr = lane & 15, cA = lane >> 4;
  f32x4 acc[4][4] = {};

  for (int t = 0; t < NT; ++t) {
    if (t < NT - 1) vmwait<4>(); else vmwait<0>();
    __builtin_amdgcn_s_barrier();
    if (t + 2 < NT) {
      u16* nxt = lds + ((t + 2) % 3) * BUFU;
      stage128(GA, lda, (t + 2) * 32, nxt, tid);
      stage128(GB, ldb, (t + 2) * 32, nxt + HALF, tid);
    }
    const u16* cur = lds + (t % 3) * BUFU;
    bf16x8 a[4], b[4];
#pragma unroll
    for (int m = 0; m < 4; ++m) a[m] = fr4(cur, wr + m * 16 + lr, cA);
#pragma unroll
    for (int n = 0; n < 4; ++n) b[n] = fr4(cur + HALF, wc + n * 16 + lr, cA);
#pragma unroll
    for (int m = 0; m < 4; ++m)
#pragma unroll
      for (int n = 0; n < 4; ++n)
        acc[m][n] = __builtin_amdgcn_mfma_f32_16x16x32_bf16(a[m], b[n],
                                                            acc[m][n], 0, 0, 0);
  }

  const int rr = (lane >> 4) << 2;
  float ps = preScale, mul = 1.0f;
  if constexpr (EPI == 1) {
    ps = (z == 0) ? preScale : 1.0f;
    mul = (z == 0) ? esp[0] : 1.0f;
  }
#pragma unroll
  for (int m = 0; m < 4; ++m) {
#pragma unroll
    for (int n = 0; n < 4; ++n) {
      const int col = (int)tN + wc + n * 16 + lr;
#pragma unroll
      for (int r = 0; r < 4; ++r) {
        const long long row = tM + wr + m * 16 + rr + r;
        const float v = acc[m][n][r];
        if constexpr (EPI == 0) {
          const int g = col >> 10, cc = col & 1023;
          if (g == 0) ((u16*)C0)[row * 2048 + cc] = f2b((v + b0[cc]) * 0.03125f);
          else        ((u16*)C1)[row * 2048 + cc] = f2b(v + b1[cc]);
        } else if constexpr (EPI == 1) {
          const float tt = v * ps + b0[col];
          const float sg = 1.f / (1.f + __expf(-tt));
          ((u16*)C0)[z * sCz + row * ldc + col] = f2b(mul * cospif(sg));
        } else if constexpr (EPI == 2) {
          ((u16*)C0)[z * sCz + row * ldc + col] = f2b(v);
        } else if constexpr (EPI == 3) {
          ((float*)C0)[z * sCz + row * ldc + col] = v + b0[col];
        } else {
          ((float*)C0)[z * sCz + row * ldc + col] = v;
        }
      }
    }
  }
}

// ---------------------------------------------------------------------------
// wide_core: A-frag-reuse wide-wave GEMM (r15: 857 TF, MfmaUtil 36%).
// Block 128x256, BK=32, 4 waves (2Mx2N), wave 64x128: 12 ds_read_b128 per
// 32 MFMA. 3x24KB LDS (2 blocks/CU), depth-2 counted vmcnt(6). f32 out.
// ---------------------------------------------------------------------------
__device__ __forceinline__ void wide_core_f32(
    u16* lds, int bx, int by, int z,
    const u16* __restrict__ A, long long lda, long long sAz,
    const u16* __restrict__ B, long long ldb, long long sBz,
    float* __restrict__ C, long long ldc, long long sCz, int K) {
  constexpr int AS = 4096;            // u16: A slice 128x32
  constexpr int BUFU = AS + 8192;     // 24 KB
  const long long tM = (long long)by * 128;
  const long long tN = (long long)bx * 256;
  const u16* GA = A + z * sAz + tM * lda;
  const u16* GB = B + z * sBz + tN * ldb;
  const int tid = threadIdx.x;
  const int NT = K >> 5;

#define STAGE_W(kb, buf)                                         \
  do {                                                           \
    stage128(GA, lda, (kb), (buf), tid);                         \
    stage128(GB, ldb, (kb), (buf) + AS, tid);                    \
    stage128(GB + 128 * ldb, ldb, (kb), (buf) + AS + 4096, tid); \
  } while (0)

  STAGE_W(0, lds);
  STAGE_W(32, lds + BUFU);

  const int wid = tid >> 6, lane = tid & 63;
  const int wr = (wid >> 1) * 64, wc = (wid & 1) * 128;
  const int lr = lane & 15, cA = lane >> 4;
  f32x4 acc[4][8] = {};

  for (int t = 0; t < NT; ++t) {
    if (t < NT - 1) vmwait<6>(); else vmwait<0>();
    __builtin_amdgcn_s_barrier();
    if (t + 2 < NT) STAGE_W((t + 2) * 32, lds + ((t + 2) % 3) * BUFU);
    const u16* cur = lds + (t % 3) * BUFU;
    const u16* Bs = cur + AS + (wid & 1) * 4096;  // wave's 128-row B sub-slab
    bf16x8 a[4], b[8];
#pragma unroll
    for (int m = 0; m < 4; ++m) a[m] = fr4(cur, wr + m * 16 + lr, cA);
#pragma unroll
    for (int n = 0; n < 8; ++n) b[n] = fr4(Bs, n * 16 + lr, cA);
#pragma unroll
    for (int m = 0; m < 4; ++m)
#pragma unroll
      for (int n = 0; n < 8; ++n)
        acc[m][n] = __builtin_amdgcn_mfma_f32_16x16x32_bf16(a[m], b[n],
                                                            acc[m][n], 0, 0, 0);
  }
#undef STAGE_W

  const int rr = (lane >> 4) << 2;
#pragma unroll
  for (int m = 0; m < 4; ++m) {
#pragma unroll
    for (int n = 0; n < 8; ++n) {
      const int col = (int)tN + wc + n * 16 + lr;
#pragma unroll
      for (int r = 0; r < 4; ++r) {
        const long long row = tM + wr + m * 16 + rr + r;
        C[z * sCz + row * ldc + col] = acc[m][n][r];
      }
    }
  }
}

// scores: logits = Qcat @ Kcat^T (wide, f32 out), grid 512 @2/CU exact fill
__global__ __launch_bounds__(256, 2) void e3s(
    const u16* __restrict__ A, long long lda, long long sAz,
    const u16* __restrict__ B, long long ldb, long long sBz,
    float* __restrict__ C, long long ldc, long long sCz, int K) {
  __shared__ __align__(16) u16 lds[3 * 12288];
  int bx, by;
  swz_xcd(blockIdx.y * gridDim.x + blockIdx.x, gridDim.x * gridDim.y,
          gridDim.x, bx, by);
  wide_core_f32(lds, bx, by, blockIdx.z, A, lda, sAz, B, ldb, sBz,
                C, ldc, sCz, K);
}

// final: out = ATT @ XVT^T + bfin (narrow, 512 blocks @ 3/CU)
template <int EPI>
__global__ __launch_bounds__(256, 3) void e3p(
    const u16* __restrict__ A, long long lda, long long sAz,
    const u16* __restrict__ B, long long ldb, long long sBz,
    void* __restrict__ C0, long long ldc, long long sCz, int K,
    const float* __restrict__ b0) {
  __shared__ __align__(16) u16 lds[3 * 8192];
  int bx, by;
  swz_xcd(blockIdx.y * gridDim.x + blockIdx.x, gridDim.x * gridDim.y,
          gridDim.x, bx, by);
  gemm_core<EPI>(lds, bx, by, blockIdx.z, A, lda, sAz, B, ldb, sBz,
                 C0, nullptr, ldc, sCz, K, b0, nullptr, 1.f, nullptr);
}

// merged narrow (r15-proven): QK projection (0..1023) + WvoT prep (1024..1087)
__global__ __launch_bounds__(256, 3) void qk_wvo(
    const u16* __restrict__ XB, u16* __restrict__ WT,
    u16* __restrict__ Qc, u16* __restrict__ Kc,
    const float* __restrict__ bq, const float* __restrict__ bk) {
  __shared__ __align__(16) u16 lds[3 * 8192];
  const int id = blockIdx.x;
  if (id < 1024) {
    int bx, by;
    swz_xcd(id, 1024, 16, bx, by);
    gemm_core<0>(lds, bx, by, 0, XB, 1024, 0, WT, 1024, 0,
                 Qc, Kc, 2048, 0, 1024, bq, bk, 1.f, nullptr);
  } else {
    int bx, by;
    swz_xcd(id - 1024, 64, 8, bx, by);
    gemm_core<2>(lds, bx, by, 0, WT + (3LL << 20), 1024, 0,
                 WT + (4LL << 20), 1024, 0, WT + (5LL << 20), nullptr,
                 1024, 0, 1024, nullptr, nullptr, 1.f, nullptr);
  }
}

// merged narrow (r15-proven): theta (0..1023) + XVT (1024..1535)
// 1536 blocks @ 3/CU = 2 exact resident rounds, role-sequential.
__global__ __launch_bounds__(256, 3) void theta_xvt(
    u16* __restrict__ Qcat, const u16* __restrict__ WT,
    const u16* __restrict__ XB, u16* __restrict__ XVT_,
    const float* __restrict__ bt, const float* __restrict__ esp) {
  __shared__ __align__(16) u16 lds[3 * 8192];
  const int id = blockIdx.x;
  if (id < 1024) {
    const int z = id >> 9;
    int bx, by;
    swz_xcd(id & 511, 512, 8, bx, by);
    gemm_core<1>(lds, bx, by, z, Qcat, 2048, 16777216LL,
                 WT + (2LL << 20), 1024, 0, Qcat + 1024, nullptr,
                 2048, 16777216LL, 1024, bt, nullptr, 32.f, esp);
  } else {
    const int e = id - 1024, z = e >> 7;
    int bx, by;
    swz_xcd(e & 127, 128, 16, bx, by);
    gemm_core<2>(lds, bx, by, z, WT + (5LL << 20), 1024, 0,
                 XB, 1024, 2097152LL, XVT_, nullptr,
                 2048, 2097152LL, 1024, nullptr, nullptr, 1.f, nullptr);
  }
}

// merged prep: cvt_x (0..8191) + cvt_w (8192..13311) + bias_fold (13312..14335)
__global__ __launch_bounds__(256) void prep_all(
    const float* __restrict__ x,
    const float* __restrict__ Wq, const float* __restrict__ Wk,
    const float* __restrict__ Wt, const float* __restrict__ Wo,
    const float* __restrict__ Wv, const float* __restrict__ bv,
    const float* __restrict__ bo,
    u16* __restrict__ XB, u16* __restrict__ WT, float* __restrict__ BF) {
  __shared__ float sh[32][33];
  const int id = blockIdx.x;
  const int thr = threadIdx.x;
  if (id < 8192) {
    const int i = id * 256 + thr;
    float4 v = ((const float4*)x)[i];
    ((ushort4*)XB)[i] = make_ushort4(f2b(v.x), f2b(v.y), f2b(v.z), f2b(v.w));
  } else if (id < 13312) {
    const int w = id - 8192;
    const int z = w >> 10, rem = w & 1023;
    const int cx = rem & 31, cy = rem >> 5;
    const float* W = (z == 0) ? Wq : (z == 1) ? Wk : (z == 2) ? Wt
                   : (z == 3) ? Wo : Wv;
    u16* D = WT + ((long long)z << 20);
    const int c0 = cx * 32, r0 = cy * 32;
    const int tx = thr & 31, ty = thr >> 5;
    if (z == 4) {
#pragma unroll
      for (int i = 0; i < 4; ++i) {
        const long long idx = (long long)(r0 + ty + i * 8) * 1024 + c0 + tx;
        D[idx] = f2b(W[idx]);
      }
      return;
    }
#pragma unroll
    for (int i = 0; i < 4; ++i)
      sh[ty + i * 8][tx] = W[(long long)(r0 + ty + i * 8) * 1024 + c0 + tx];
    __syncthreads();
#pragma unroll
    for (int i = 0; i < 4; ++i)
      D[(long long)(c0 + ty + i * 8) * 1024 + r0 + tx] = f2b(sh[tx][ty + i * 8]);
  } else {
    const int i = id - 13312;
    float acc = 0.f;
    for (int k = thr; k < 1024; k += 256)
      acc += bv[k] * Wo[(long long)k * 1024 + i];
    float* red = &sh[0][0];
    red[thr] = acc;
    __syncthreads();
    for (int s = 128; s > 0; s >>= 1) {
      if (thr < s) red[thr] += red[thr + s];
      __syncthreads();
    }
    if (thr == 0) BF[i] = red[0] + bo[i];
  }
}

// row softmax over [8192][2048]: fp32 in-place + bf16 copy
__global__ __launch_bounds__(256) void softmax_rows(float* __restrict__ L,
                                                    u16* __restrict__ AB) {
  const long long row = blockIdx.x;
  float4* p4 = (float4*)(L + row * 2048);
  const int tid = threadIdx.x;
  float4 a = p4[tid], b = p4[tid + 256];
  float m = fmaxf(fmaxf(fmaxf(a.x, a.y), fmaxf(a.z, a.w)),
                  fmaxf(fmaxf(b.x, b.y), fmaxf(b.z, b.w)));
#pragma unroll
  for (int o = 32; o > 0; o >>= 1) m = fmaxf(m, __shfl_xor(m, o));
  __shared__ float rmax[4], rsum[4];
  const int wid = tid >> 6, lane = tid & 63;
  if (lane == 0) rmax[wid] = m;
  __syncthreads();
  m = fmaxf(fmaxf(rmax[0], rmax[1]), fmaxf(rmax[2], rmax[3]));
  a.x = __expf(a.x - m); a.y = __expf(a.y - m);
  a.z = __expf(a.z - m); a.w = __expf(a.w - m);
  b.x = __expf(b.x - m); b.y = __expf(b.y - m);
  b.z = __expf(b.z - m); b.w = __expf(b.w - m);
  float s = a.x + a.y + a.z + a.w + b.x + b.y + b.z + b.w;
#pragma unroll
  for (int o = 32; o > 0; o >>= 1) s += __shfl_xor(s, o);
  if (lane == 0) rsum[wid] = s;
  __syncthreads();
  s = rsum[0] + rsum[1] + rsum[2] + rsum[3];
  const float inv = 1.0f / s;
  a.x *= inv; a.y *= inv; a.z *= inv; a.w *= inv;
  b.x *= inv; b.y *= inv; b.z *= inv; b.w *= inv;
  p4[tid] = a;
  p4[tid + 256] = b;
  ushort4* o4 = (ushort4*)(AB + row * 2048);
  o4[tid]       = make_ushort4(f2b(a.x), f2b(a.y), f2b(a.z), f2b(a.w));
  o4[tid + 256] = make_ushort4(f2b(b.x), f2b(b.y), f2b(b.z), f2b(b.w));
}

extern "C" void kernel_launch(void* const* d_in, const int* in_sizes, int n_in,
                              void* d_out, int out_size, void* d_ws,
                              size_t ws_size, hipStream_t stream) {
  const float* x  = (const float*)d_in[0];
  const float* Wq = (const float*)d_in[1];
  const float* bq = (const float*)d_in[2];
  const float* Wk = (const float*)d_in[3];
  const float* bk = (const float*)d_in[4];
  const float* Wv = (const float*)d_in[5];
  const float* bv = (const float*)d_in[6];
  const float* Wt = (const float*)d_in[7];
  const float* bt = (const float*)d_in[8];
  const float* Wo = (const float*)d_in[9];
  const float* bo = (const float*)d_in[10];
  const float* es = (const float*)d_in[11];

  char* ws = (char*)d_ws;
  // WT slots (1 MiB-u16 = 2 MB each): 0=WqT 1=WkT 2=WtT 3=WoT 4=WvB 5=WvoT
  u16* WT    = (u16*)(ws);                   // 12 MB
  float* BF  = (float*)(ws + 12582912);      // bfin[1024]
  u16* XB    = (u16*)(ws + 12587008);        // [8192,1024] bf16
  u16* Qcat  = (u16*)(ws + 29364224);        // [8192,2048]: Q/32 | es*r_q
  u16* Kcat  = Qcat + 16777216;              // [8192,2048]: K | r_k
  u16* XVT   = (u16*)(ws + 96473088);        // [4][1024,2048]: (x@Wvo)^T
  u16* ATT   = Qcat;                         // attn bf16 reuse

  float* outO = (float*)d_out;               // [4,2048,1024]
  float* outA = outO + 8388608;              // [4,2048,2048]

  // 1. all preps (cvt_x + cvt_w + bias_fold)
  prep_all<<<14336, 256, 0, stream>>>(x, Wq, Wk, Wt, Wo, Wv, bv, bo,
                                      XB, WT, BF);
  // 2. QK projection + WvoT prep (narrow, 1088 @ 3/CU)
  qk_wvo<<<1088, 256, 0, stream>>>(XB, WT, Qcat, Kcat, bq, bk);
  // 3. theta + XVT (narrow, 1536 @ 3/CU, role-sequential — r15 champion)
  theta_xvt<<<1536, 256, 0, stream>>>(Qcat, WT, XB, XVT, bt, es);
  // 4. logits = Qcat @ Kcat^T (K=2048) -> outA (wide, grid 512 exact fill)
  e3s<<<dim3(8, 16, 4), 256, 0, stream>>>(
      Qcat, 2048, 4194304, Kcat, 2048, 4194304,
      outA, 2048, 4194304, 2048);
  // 5. softmax in-place + bf16 copy
  softmax_rows<<<8192, 256, 0, stream>>>(outA, ATT);
  // 6. out = ATT @ XVT^T + bfin (narrow, grid 512 @ 3/CU)
  e3p<3><<<dim3(8, 16, 4), 256, 0, stream>>>(
      ATT, 2048, 4194304, XVT, 2048, 2097152,
      outO, 1024, 2097152, 2048, BF);
}

// Round 20
// 302.292 us; speedup vs baseline: 1.0297x; 1.0138x over previous
//
#include <hip/hip_runtime.h>
#include <cstdint>

typedef unsigned short u16;
typedef __attribute__((ext_vector_type(8))) short bf16x8;
typedef __attribute__((ext_vector_type(4))) float f32x4;

__device__ __forceinline__ u16 f2b(float x) {
  unsigned u = __float_as_uint(x);
  u += 0x7FFFu + ((u >> 16) & 1u);
  return (u16)(u >> 16);
}

// cos(pi*sigmoid(t)) = -sin(pi*(sigmoid(t)-0.5)); |u|<=0.5 odd poly, deg 7,
// max err ~1.6e-4 (<< bf16 ulp). Replaces fract+v_cos with 4 FMA.
__device__ __forceinline__ float cos_pi_sigmoid(float t) {
  const float sg = 1.f / (1.f + __expf(-t));
  const float u = sg - 0.5f;
  const float u2 = u * u;
  // sin(pi*u) = u*(pi - 5.16771278*u2 + 2.55016404*u2^2 - 0.59926453*u2^3)
  float p = -0.59926453f;
  p = p * u2 + 2.55016404f;
  p = p * u2 - 5.16771278f;
  p = p * u2 + 3.14159265f;
  return -(u * p);
}

__device__ __forceinline__ void gload16(const void* g, void* l) {
  __builtin_amdgcn_global_load_lds(
      (const __attribute__((address_space(1))) void*)g,
      (__attribute__((address_space(3))) void*)l, 16, 0, 0);
}

template <int N>
__device__ __forceinline__ void vmwait() {
  if constexpr (N == 0) asm volatile("s_waitcnt vmcnt(0)" ::: "memory");
  else if constexpr (N == 4) asm volatile("s_waitcnt vmcnt(4)" ::: "memory");
  else if constexpr (N == 6) asm volatile("s_waitcnt vmcnt(6)" ::: "memory");
}

// ---------------------------------------------------------------------------
// 128x32 bf16 slice as 64 virtual rows of 128 B (8 x 16 B chunks), chunk
// XOR (vrow&7): measured ZERO bank conflicts (r10-r19). Both-sides rule
// (m231): LDS dest linear, global source inverse-swizzled, read same
// involution.
// ---------------------------------------------------------------------------
__device__ __forceinline__ void stage128(const u16* __restrict__ G,
                                         long long ld, int kb,
                                         u16* Ldst, int tid) {
#pragma unroll
  for (int j = 0; j < 2; ++j) {
    const int P = j * 256 + tid;
    const int vr = P >> 3;
    const int ch = (P & 7) ^ (vr & 7);
    const int r = vr * 2 + (ch >> 2), c = ch & 3;
    gload16(G + (long long)r * ld + kb + c * 8, Ldst + P * 8);
  }
}

__device__ __forceinline__ bf16x8 fr4(const u16* R, int row, int chunk) {
  const int vr = row >> 1;
  const int ch = (((row & 1) << 2) | chunk) ^ (vr & 7);
  return *(const bf16x8*)(R + vr * 64 + ch * 8);
}

// XCD-aware bijective swizzle within a role's sub-grid (S % 8 == 0)
__device__ __forceinline__ void swz_xcd(int hw, int S, int gx,
                                        int& bx, int& by) {
  const int l = (hw & 7) * (S >> 3) + (hw >> 3);
  bx = l % gx;
  by = l / gx;
}

// ---------------------------------------------------------------------------
// gemm_core: 128x128 tile, BK=32, 4 waves (wave 64x64), 3x16KB LDS,
// depth-2 counted vmcnt(4). 741 TF class (r10-r19).
// EPI: 0=QK split  1=theta->cat half  2=bf16  3=f32+colbias  4=f32 plain
// ---------------------------------------------------------------------------
template <int EPI>
__device__ __forceinline__ void gemm_core(
    u16* lds, int bx, int by, int z,
    const u16* __restrict__ A, long long lda, long long sAz,
    const u16* __restrict__ B, long long ldb, long long sBz,
    void* __restrict__ C0, void* __restrict__ C1,
    long long ldc, long long sCz, int K,
    const float* __restrict__ b0, const float* __restrict__ b1,
    float preScale, const float* __restrict__ esp) {
  constexpr int HALF = 4096;
  constexpr int BUFU = 2 * HALF;
  const long long tM = (long long)by * 128;
  const long long tN = (long long)bx * 128;
  const u16* GA = A + z * sAz + tM * lda;
  const u16* GB = B + z * sBz + tN * ldb;
  const int tid = threadIdx.x;
  const int NT = K >> 5;

  stage128(GA, lda, 0, lds, tid);
  stage128(GB, ldb, 0, lds + HALF, tid);
  stage128(GA, lda, 32, lds + BUFU, tid);
  stage128(GB, ldb, 32, lds + BUFU + HALF, tid);

  const int wid = tid >> 6, lane = tid & 63;
  const int wr = (wid >> 1) * 64, wc = (wid & 1) * 64;
  const int lr = lane & 15, cA = lane >> 4;
  f32x4 acc[4][4] = {};

  for (int t = 0; t < NT; ++t) {
    if (t < NT - 1) vmwait<4>(); else vmwait<0>();
    __builtin_amdgcn_s_barrier();
    if (t + 2 < NT) {
      u16* nxt = lds + ((t + 2) % 3) * BUFU;
      stage128(GA, lda, (t + 2) * 32, nxt, tid);
      stage128(GB, ldb, (t + 2) * 32, nxt + HALF, tid);
    }
    const u16* cur = lds + (t % 3) * BUFU;
    bf16x8 a[4], b[4];
#pragma unroll
    for (int m = 0; m < 4; ++m) a[m] = fr4(cur, wr + m * 16 + lr, cA);
#pragma unroll
    for (int n = 0; n < 4; ++n) b[n] = fr4(cur + HALF, wc + n * 16 + lr, cA);
#pragma unroll
    for (int m = 0; m < 4; ++m)
#pragma unroll
      for (int n = 0; n < 4; ++n)
        acc[m][n] = __builtin_amdgcn_mfma_f32_16x16x32_bf16(a[m], b[n],
                                                            acc[m][n], 0, 0, 0);
  }

  const int rr = (lane >> 4) << 2;
  float ps = preScale, mul = 1.0f;
  if constexpr (EPI == 1) {
    ps = (z == 0) ? preScale : 1.0f;
    mul = (z == 0) ? esp[0] : 1.0f;
  }
#pragma unroll
  for (int m = 0; m < 4; ++m) {
#pragma unroll
    for (int n = 0; n < 4; ++n) {
      const int col = (int)tN + wc + n * 16 + lr;
#pragma unroll
      for (int r = 0; r < 4; ++r) {
        const long long row = tM + wr + m * 16 + rr + r;
        const float v = acc[m][n][r];
        if constexpr (EPI == 0) {
          const int g = col >> 10, cc = col & 1023;
          if (g == 0) ((u16*)C0)[row * 2048 + cc] = f2b((v + b0[cc]) * 0.03125f);
          else        ((u16*)C1)[row * 2048 + cc] = f2b(v + b1[cc]);
        } else if constexpr (EPI == 1) {
          const float tt = v * ps + b0[col];
          ((u16*)C0)[z * sCz + row * ldc + col] = f2b(mul * cos_pi_sigmoid(tt));
        } else if constexpr (EPI == 2) {
          ((u16*)C0)[z * sCz + row * ldc + col] = f2b(v);
        } else if constexpr (EPI == 3) {
          ((float*)C0)[z * sCz + row * ldc + col] = v + b0[col];
        } else {
          ((float*)C0)[z * sCz + row * ldc + col] = v;
        }
      }
    }
  }
}

// ---------------------------------------------------------------------------
// wide_core: A-frag-reuse wide-wave GEMM (r15/r19: 857 TF, MfmaUtil 36%).
// Block 128x256, BK=32, 4 waves (2Mx2N), wave 64x128: 12 ds_read_b128 per
// 32 MFMA. 3x24KB LDS (2 blocks/CU), depth-2 counted vmcnt(6). f32 out.
// ---------------------------------------------------------------------------
__device__ __forceinline__ void wide_core_f32(
    u16* lds, int bx, int by, int z,
    const u16* __restrict__ A, long long lda, long long sAz,
    const u16* __restrict__ B, long long ldb, long long sBz,
    float* __restrict__ C, long long ldc, long long sCz, int K) {
  constexpr int AS = 4096;            // u16: A slice 128x32
  constexpr int BUFU = AS + 8192;     // 24 KB
  const long long tM = (long long)by * 128;
  const long long tN = (long long)bx * 256;
  const u16* GA = A + z * sAz + tM * lda;
  const u16* GB = B + z * sBz + tN * ldb;
  const int tid = threadIdx.x;
  const int NT = K >> 5;

#define STAGE_W(kb, buf)                                         \
  do {                                                           \
    stage128(GA, lda, (kb), (buf), tid);                         \
    stage128(GB, ldb, (kb), (buf) + AS, tid);                    \
    stage128(GB + 128 * ldb, ldb, (kb), (buf) + AS + 4096, tid); \
  } while (0)

  STAGE_W(0, lds);
  STAGE_W(32, lds + BUFU);

  const int wid = tid >> 6, lane = tid & 63;
  const int wr = (wid >> 1) * 64, wc = (wid & 1) * 128;
  const int lr = lane & 15, cA = lane >> 4;
  f32x4 acc[4][8] = {};

  for (int t = 0; t < NT; ++t) {
    if (t < NT - 1) vmwait<6>(); else vmwait<0>();
    __builtin_amdgcn_s_barrier();
    if (t + 2 < NT) STAGE_W((t + 2) * 32, lds + ((t + 2) % 3) * BUFU);
    const u16* cur = lds + (t % 3) * BUFU;
    const u16* Bs = cur + AS + (wid & 1) * 4096;  // wave's 128-row B sub-slab
    bf16x8 a[4], b[8];
#pragma unroll
    for (int m = 0; m < 4; ++m) a[m] = fr4(cur, wr + m * 16 + lr, cA);
#pragma unroll
    for (int n = 0; n < 8; ++n) b[n] = fr4(Bs, n * 16 + lr, cA);
#pragma unroll
    for (int m = 0; m < 4; ++m)
#pragma unroll
      for (int n = 0; n < 8; ++n)
        acc[m][n] = __builtin_amdgcn_mfma_f32_16x16x32_bf16(a[m], b[n],
                                                            acc[m][n], 0, 0, 0);
  }
#undef STAGE_W

  const int rr = (lane >> 4) << 2;
#pragma unroll
  for (int m = 0; m < 4; ++m) {
#pragma unroll
    for (int n = 0; n < 8; ++n) {
      const int col = (int)tN + wc + n * 16 + lr;
#pragma unroll
      for (int r = 0; r < 4; ++r) {
        const long long row = tM + wr + m * 16 + rr + r;
        C[z * sCz + row * ldc + col] = acc[m][n][r];
      }
    }
  }
}

// scores: logits = Qcat @ Kcat^T (wide, f32 out), grid 512 @2/CU exact fill
__global__ __launch_bounds__(256, 2) void e3s(
    const u16* __restrict__ A, long long lda, long long sAz,
    const u16* __restrict__ B, long long ldb, long long sBz,
    float* __restrict__ C, long long ldc, long long sCz, int K) {
  __shared__ __align__(16) u16 lds[3 * 12288];
  int bx, by;
  swz_xcd(blockIdx.y * gridDim.x + blockIdx.x, gridDim.x * gridDim.y,
          gridDim.x, bx, by);
  wide_core_f32(lds, bx, by, blockIdx.z, A, lda, sAz, B, ldb, sBz,
                C, ldc, sCz, K);
}

// final: out = ATT @ XVT^T + bfin (narrow, 512 blocks @ 3/CU)
template <int EPI>
__global__ __launch_bounds__(256, 3) void e3p(
    const u16* __restrict__ A, long long lda, long long sAz,
    const u16* __restrict__ B, long long ldb, long long sBz,
    void* __restrict__ C0, long long ldc, long long sCz, int K,
    const float* __restrict__ b0) {
  __shared__ __align__(16) u16 lds[3 * 8192];
  int bx, by;
  swz_xcd(blockIdx.y * gridDim.x + blockIdx.x, gridDim.x * gridDim.y,
          gridDim.x, bx, by);
  gemm_core<EPI>(lds, bx, by, blockIdx.z, A, lda, sAz, B, ldb, sBz,
                 C0, nullptr, ldc, sCz, K, b0, nullptr, 1.f, nullptr);
}

// merged narrow: QK projection (0..1023) + WvoT prep (1024..1087)
__global__ __launch_bounds__(256, 3) void qk_wvo(
    const u16* __restrict__ XB, u16* __restrict__ WT,
    u16* __restrict__ Qc, u16* __restrict__ Kc,
    const float* __restrict__ bq, const float* __restrict__ bk) {
  __shared__ __align__(16) u16 lds[3 * 8192];
  const int id = blockIdx.x;
  if (id < 1024) {
    int bx, by;
    swz_xcd(id, 1024, 16, bx, by);
    gemm_core<0>(lds, bx, by, 0, XB, 1024, 0, WT, 1024, 0,
                 Qc, Kc, 2048, 0, 1024, bq, bk, 1.f, nullptr);
  } else {
    int bx, by;
    swz_xcd(id - 1024, 64, 8, bx, by);
    gemm_core<2>(lds, bx, by, 0, WT + (3LL << 20), 1024, 0,
                 WT + (4LL << 20), 1024, 0, WT + (5LL << 20), nullptr,
                 1024, 0, 1024, nullptr, nullptr, 1.f, nullptr);
  }
}

// merged narrow: theta (0..1023) + XVT (1024..1535), role-sequential
__global__ __launch_bounds__(256, 3) void theta_xvt(
    u16* __restrict__ Qcat, const u16* __restrict__ WT,
    const u16* __restrict__ XB, u16* __restrict__ XVT_,
    const float* __restrict__ bt, const float* __restrict__ esp) {
  __shared__ __align__(16) u16 lds[3 * 8192];
  const int id = blockIdx.x;
  if (id < 1024) {
    const int z = id >> 9;
    int bx, by;
    swz_xcd(id & 511, 512, 8, bx, by);
    gemm_core<1>(lds, bx, by, z, Qcat, 2048, 16777216LL,
                 WT + (2LL << 20), 1024, 0, Qcat + 1024, nullptr,
                 2048, 16777216LL, 1024, bt, nullptr, 32.f, esp);
  } else {
    const int e = id - 1024, z = e >> 7;
    int bx, by;
    swz_xcd(e & 127, 128, 16, bx, by);
    gemm_core<2>(lds, bx, by, z, WT + (5LL << 20), 1024, 0,
                 XB, 1024, 2097152LL, XVT_, nullptr,
                 2048, 2097152LL, 1024, nullptr, nullptr, 1.f, nullptr);
  }
}

// merged prep: cvt_x (0..8191) + cvt_w (8192..13311) + bias_fold (13312..14335)
__global__ __launch_bounds__(256) void prep_all(
    const float* __restrict__ x,
    const float* __restrict__ Wq, const float* __restrict__ Wk,
    const float* __restrict__ Wt, const float* __restrict__ Wo,
    const float* __restrict__ Wv, const float* __restrict__ bv,
    const float* __restrict__ bo,
    u16* __restrict__ XB, u16* __restrict__ WT, float* __restrict__ BF) {
  __shared__ float sh[32][33];
  const int id = blockIdx.x;
  const int thr = threadIdx.x;
  if (id < 8192) {
    const int i = id * 256 + thr;
    float4 v = ((const float4*)x)[i];
    ((ushort4*)XB)[i] = make_ushort4(f2b(v.x), f2b(v.y), f2b(v.z), f2b(v.w));
  } else if (id < 13312) {
    const int w = id - 8192;
    const int z = w >> 10, rem = w & 1023;
    const int cx = rem & 31, cy = rem >> 5;
    const float* W = (z == 0) ? Wq : (z == 1) ? Wk : (z == 2) ? Wt
                   : (z == 3) ? Wo : Wv;
    u16* D = WT + ((long long)z << 20);
    const int c0 = cx * 32, r0 = cy * 32;
    const int tx = thr & 31, ty = thr >> 5;
    if (z == 4) {
#pragma unroll
      for (int i = 0; i < 4; ++i) {
        const long long idx = (long long)(r0 + ty + i * 8) * 1024 + c0 + tx;
        D[idx] = f2b(W[idx]);
      }
      return;
    }
#pragma unroll
    for (int i = 0; i < 4; ++i)
      sh[ty + i * 8][tx] = W[(long long)(r0 + ty + i * 8) * 1024 + c0 + tx];
    __syncthreads();
#pragma unroll
    for (int i = 0; i < 4; ++i)
      D[(long long)(c0 + ty + i * 8) * 1024 + r0 + tx] = f2b(sh[tx][ty + i * 8]);
  } else {
    const int i = id - 13312;
    float acc = 0.f;
    for (int k = thr; k < 1024; k += 256)
      acc += bv[k] * Wo[(long long)k * 1024 + i];
    float* red = &sh[0][0];
    red[thr] = acc;
    __syncthreads();
    for (int s = 128; s > 0; s >>= 1) {
      if (thr < s) red[thr] += red[thr + s];
      __syncthreads();
    }
    if (thr == 0) BF[i] = red[0] + bo[i];
  }
}

// row softmax over [8192][2048]: fp32 in-place + bf16 copy
__global__ __launch_bounds__(256) void softmax_rows(float* __restrict__ L,
                                                    u16* __restrict__ AB) {
  const long long row = blockIdx.x;
  float4* p4 = (float4*)(L + row * 2048);
  const int tid = threadIdx.x;
  float4 a = p4[tid], b = p4[tid + 256];
  float m = fmaxf(fmaxf(fmaxf(a.x, a.y), fmaxf(a.z, a.w)),
                  fmaxf(fmaxf(b.x, b.y), fmaxf(b.z, b.w)));
#pragma unroll
  for (int o = 32; o > 0; o >>= 1) m = fmaxf(m, __shfl_xor(m, o));
  __shared__ float rmax[4], rsum[4];
  const int wid = tid >> 6, lane = tid & 63;
  if (lane == 0) rmax[wid] = m;
  __syncthreads();
  m = fmaxf(fmaxf(rmax[0], rmax[1]), fmaxf(rmax[2], rmax[3]));
  a.x = __expf(a.x - m); a.y = __expf(a.y - m);
  a.z = __expf(a.z - m); a.w = __expf(a.w - m);
  b.x = __expf(b.x - m); b.y = __expf(b.y - m);
  b.z = __expf(b.z - m); b.w = __expf(b.w - m);
  float s = a.x + a.y + a.z + a.w + b.x + b.y + b.z + b.w;
#pragma unroll
  for (int o = 32; o > 0; o >>= 1) s += __shfl_xor(s, o);
  if (lane == 0) rsum[wid] = s;
  __syncthreads();
  s = rsum[0] + rsum[1] + rsum[2] + rsum[3];
  const float inv = 1.0f / s;
  a.x *= inv; a.y *= inv; a.z *= inv; a.w *= inv;
  b.x *= inv; b.y *= inv; b.z *= inv; b.w *= inv;
  p4[tid] = a;
  p4[tid + 256] = b;
  ushort4* o4 = (ushort4*)(AB + row * 2048);
  o4[tid]       = make_ushort4(f2b(a.x), f2b(a.y), f2b(a.z), f2b(a.w));
  o4[tid + 256] = make_ushort4(f2b(b.x), f2b(b.y), f2b(b.z), f2b(b.w));
}

extern "C" void kernel_launch(void* const* d_in, const int* in_sizes, int n_in,
                              void* d_out, int out_size, void* d_ws,
                              size_t ws_size, hipStream_t stream) {
  const float* x  = (const float*)d_in[0];
  const float* Wq = (const float*)d_in[1];
  const float* bq = (const float*)d_in[2];
  const float* Wk = (const float*)d_in[3];
  const float* bk = (const float*)d_in[4];
  const float* Wv = (const float*)d_in[5];
  const float* bv = (const float*)d_in[6];
  const float* Wt = (const float*)d_in[7];
  const float* bt = (const float*)d_in[8];
  const float* Wo = (const float*)d_in[9];
  const float* bo = (const float*)d_in[10];
  const float* es = (const float*)d_in[11];

  char* ws = (char*)d_ws;
  // WT slots (1 MiB-u16 = 2 MB each): 0=WqT 1=WkT 2=WtT 3=WoT 4=WvB 5=WvoT
  u16* WT    = (u16*)(ws);                   // 12 MB
  float* BF  = (float*)(ws + 12582912);      // bfin[1024]
  u16* XB    = (u16*)(ws + 12587008);        // [8192,1024] bf16
  u16* Qcat  = (u16*)(ws + 29364224);        // [8192,2048]: Q/32 | es*r_q
  u16* Kcat  = Qcat + 16777216;              // [8192,2048]: K | r_k
  u16* XVT   = (u16*)(ws + 96473088);        // [4][1024,2048]: (x@Wvo)^T
  u16* ATT   = Qcat;                         // attn bf16 reuse

  float* outO = (float*)d_out;               // [4,2048,1024]
  float* outA = outO + 8388608;              // [4,2048,2048]

  // 1. all preps (cvt_x + cvt_w + bias_fold)
  prep_all<<<14336, 256, 0, stream>>>(x, Wq, Wk, Wt, Wo, Wv, bv, bo,
                                      XB, WT, BF);
  // 2. QK projection + WvoT prep (narrow, 1088 @ 3/CU)
  qk_wvo<<<1088, 256, 0, stream>>>(XB, WT, Qcat, Kcat, bq, bk);
  // 3. theta + XVT (narrow, 1536 @ 3/CU; theta epilogue now poly-based)
  theta_xvt<<<1536, 256, 0, stream>>>(Qcat, WT, XB, XVT, bt, es);
  // 4. logits = Qcat @ Kcat^T (K=2048) -> outA (wide, grid 512 exact fill)
  e3s<<<dim3(8, 16, 4), 256, 0, stream>>>(
      Qcat, 2048, 4194304, Kcat, 2048, 4194304,
      outA, 2048, 4194304, 2048);
  // 5. softmax in-place + bf16 copy
  softmax_rows<<<8192, 256, 0, stream>>>(outA, ATT);
  // 6. out = ATT @ XVT^T + bfin (narrow, grid 512 @ 3/CU)
  e3p<3><<<dim3(8, 16, 4), 256, 0, stream>>>(
      ATT, 2048, 4194304, XVT, 2048, 2097152,
      outO, 1024, 2097152, 2048, BF);
}